// Round 3
// baseline (478.221 us; speedup 1.0000x reference)
//
#include <hip/hip_runtime.h>
#include <math.h>

#define NN 8192
#define NB (NN / 2)            // 4096 row-pair blocks
#define SPARSE_WEIGHT 0.01f

// Native 4-float vector (usable with __builtin_nontemporal_load, unlike HIP's
// float4 which is a class type).
typedef float f4 __attribute__((ext_vector_type(4)));

// Workspace layout (floats):
// ws[0] = sum_cos, ws[1] = sum_sin   (prep atomics)
// ws[4 .. 4+NN)        = sj[j] = alive[j]*sin(phases[j])
// ws[4+NN .. 4+2NN)    = cj[j] = alive[j]*cos(phases[j])
// ws[4+2NN .. 4+2NN+NB)   = pk2[b]  per-block partial sum of K^2
// ws[4+3NN .. 4+3NN+NB)   = pka[b]  per-block partial sum of |K|

__device__ __forceinline__ float wave_reduce_sum(float v) {
#pragma unroll
    for (int off = 32; off > 0; off >>= 1)
        v += __shfl_down(v, off, 64);
    return v;
}

// Kernel A: per-element sin/cos prep + global sums of cos/sin for R.
__global__ __launch_bounds__(256) void prep_kernel(
        const float* __restrict__ phases,
        const float* __restrict__ alive,
        float* __restrict__ sj,
        float* __restrict__ cj,
        float* __restrict__ acc) {
    int j = blockIdx.x * blockDim.x + threadIdx.x;
    float s = 0.f, c = 0.f;
    if (j < NN) {
        float p = phases[j];
        s = sinf(p);
        c = cosf(p);
        float a = alive[j];
        sj[j] = a * s;
        cj[j] = a * c;
    }
    float ws = wave_reduce_sum(s);
    float wc = wave_reduce_sum(c);
    __shared__ float red_s[4], red_c[4];
    int lane = threadIdx.x & 63;
    int wave = threadIdx.x >> 6;
    if (lane == 0) { red_s[wave] = ws; red_c[wave] = wc; }
    __syncthreads();
    if (threadIdx.x == 0) {
        float bs = red_s[0] + red_s[1] + red_s[2] + red_s[3];
        float bc = red_c[0] + red_c[1] + red_c[2] + red_c[3];
        atomicAdd(&acc[1], bs);
        atomicAdd(&acc[0], bc);
    }
}

// Kernel B: one block per ROW PAIR (rows 2b, 2b+1). Stream both K-rows and
// dist-rows once (non-temporal — zero reuse), reuse sj/cj across the pair:
//   t1r = sum_j K*dist*sj[j],  t2r = sum_j K*dist*cj[j]   (per row)
//   k2  = sum_j K*K,           ka  = sum_j |K|            (both rows merged)
// dtheta[i] = alive[i] * (cos(p_i)*t1 - sin(p_i)*t2)
__global__ __launch_bounds__(256) void row_kernel(
        const float* __restrict__ K,
        const float* __restrict__ dist,
        const float* __restrict__ sj,
        const float* __restrict__ cj,
        const float* __restrict__ phases,
        const float* __restrict__ alive,
        float* __restrict__ dtheta,   // points at out+1
        float* __restrict__ pk2,
        float* __restrict__ pka) {
    const int b  = blockIdx.x;
    const int ia = 2 * b;
    const int ib = 2 * b + 1;
    const f4* __restrict__ Kra = (const f4*)(K    + (size_t)ia * NN);
    const f4* __restrict__ Krb = (const f4*)(K    + (size_t)ib * NN);
    const f4* __restrict__ Dra = (const f4*)(dist + (size_t)ia * NN);
    const f4* __restrict__ Drb = (const f4*)(dist + (size_t)ib * NN);
    const f4* __restrict__ S4  = (const f4*)sj;
    const f4* __restrict__ C4  = (const f4*)cj;

    float t1a = 0.f, t2a = 0.f, t1b = 0.f, t2b = 0.f, sk2 = 0.f, ska = 0.f;
#pragma unroll 4
    for (int q = threadIdx.x; q < NN / 4; q += 256) {
        f4 ka4 = __builtin_nontemporal_load(&Kra[q]);
        f4 da4 = __builtin_nontemporal_load(&Dra[q]);
        f4 kb4 = __builtin_nontemporal_load(&Krb[q]);
        f4 db4 = __builtin_nontemporal_load(&Drb[q]);
        f4 s = S4[q];
        f4 c = C4[q];
        float m;
        // row a
        m = ka4.x * da4.x; t1a += m * s.x; t2a += m * c.x;
        m = ka4.y * da4.y; t1a += m * s.y; t2a += m * c.y;
        m = ka4.z * da4.z; t1a += m * s.z; t2a += m * c.z;
        m = ka4.w * da4.w; t1a += m * s.w; t2a += m * c.w;
        // row b
        m = kb4.x * db4.x; t1b += m * s.x; t2b += m * c.x;
        m = kb4.y * db4.y; t1b += m * s.y; t2b += m * c.y;
        m = kb4.z * db4.z; t1b += m * s.z; t2b += m * c.z;
        m = kb4.w * db4.w; t1b += m * s.w; t2b += m * c.w;
        // regularizer sums over both rows
        sk2 += ka4.x * ka4.x + ka4.y * ka4.y + ka4.z * ka4.z + ka4.w * ka4.w;
        sk2 += kb4.x * kb4.x + kb4.y * kb4.y + kb4.z * kb4.z + kb4.w * kb4.w;
        ska += fabsf(ka4.x) + fabsf(ka4.y) + fabsf(ka4.z) + fabsf(ka4.w);
        ska += fabsf(kb4.x) + fabsf(kb4.y) + fabsf(kb4.z) + fabsf(kb4.w);
    }

    t1a = wave_reduce_sum(t1a);
    t2a = wave_reduce_sum(t2a);
    t1b = wave_reduce_sum(t1b);
    t2b = wave_reduce_sum(t2b);
    sk2 = wave_reduce_sum(sk2);
    ska = wave_reduce_sum(ska);

    __shared__ float red[6][4];
    int lane = threadIdx.x & 63;
    int wave = threadIdx.x >> 6;
    if (lane == 0) {
        red[0][wave] = t1a; red[1][wave] = t2a;
        red[2][wave] = t1b; red[3][wave] = t2b;
        red[4][wave] = sk2; red[5][wave] = ska;
    }
    __syncthreads();
    if (threadIdx.x == 0) {
        t1a = red[0][0] + red[0][1] + red[0][2] + red[0][3];
        t2a = red[1][0] + red[1][1] + red[1][2] + red[1][3];
        t1b = red[2][0] + red[2][1] + red[2][2] + red[2][3];
        t2b = red[3][0] + red[3][1] + red[3][2] + red[3][3];
        sk2 = red[4][0] + red[4][1] + red[4][2] + red[4][3];
        ska = red[5][0] + red[5][1] + red[5][2] + red[5][3];
        float pa = phases[ia];
        float pb = phases[ib];
        dtheta[ia] = alive[ia] * (cosf(pa) * t1a - sinf(pa) * t2a);
        dtheta[ib] = alive[ib] * (cosf(pb) * t1b - sinf(pb) * t2b);
        pk2[b] = sk2;   // plain store — no atomic
        pka[b] = ska;
    }
}

// Kernel C: reduce the NB per-block partials + finalize scalars.
__global__ __launch_bounds__(1024) void finalize_kernel(
        const float* __restrict__ acc,
        const float* __restrict__ pk2,
        const float* __restrict__ pka,
        float* __restrict__ out) {
    float k2 = 0.f, ka = 0.f;
    for (int j = threadIdx.x; j < NB; j += 1024) {
        k2 += pk2[j];
        ka += pka[j];
    }
    k2 = wave_reduce_sum(k2);
    ka = wave_reduce_sum(ka);
    __shared__ float rk2[16], rka[16];
    int lane = threadIdx.x & 63;
    int wave = threadIdx.x >> 6;
    if (lane == 0) { rk2[wave] = k2; rka[wave] = ka; }
    __syncthreads();
    if (threadIdx.x == 0) {
        float sk2 = 0.f, ska = 0.f;
#pragma unroll
        for (int w = 0; w < 16; ++w) { sk2 += rk2[w]; ska += rka[w]; }
        float cs = acc[0] / (float)NN;
        float ss = acc[1] / (float)NN;
        float R = sqrtf(cs * cs + ss * ss);
        out[0] = R;
        out[NN + 1] = 1.0f - R + 0.01f * sqrtf(sk2) + SPARSE_WEIGHT * ska;
    }
}

extern "C" void kernel_launch(void* const* d_in, const int* in_sizes, int n_in,
                              void* d_out, int out_size, void* d_ws, size_t ws_size,
                              hipStream_t stream) {
    const float* phases = (const float*)d_in[0];
    const float* alive  = (const float*)d_in[1];
    const float* dist   = (const float*)d_in[2];
    const float* K      = (const float*)d_in[3];
    float* out = (float*)d_out;
    float* ws  = (float*)d_ws;

    float* acc = ws;                 // 4 floats (0,1 used)
    float* sj  = ws + 4;             // NN floats
    float* cj  = ws + 4 + NN;        // NN floats
    float* pk2 = ws + 4 + 2 * NN;    // NB floats
    float* pka = ws + 4 + 3 * NN;    // NB floats

    (void)hipMemsetAsync(acc, 0, 4 * sizeof(float), stream);

    prep_kernel<<<NN / 256, 256, 0, stream>>>(phases, alive, sj, cj, acc);
    row_kernel<<<NB, 256, 0, stream>>>(K, dist, sj, cj, phases, alive, out + 1, pk2, pka);
    finalize_kernel<<<1, 1024, 0, stream>>>(acc, pk2, pka, out);
}